// Round 2
// baseline (48.016 us; speedup 1.0000x reference)
//
#include <hip/hip_runtime.h>

// Output = encode_output.sum(axis=1): [B, S, EOUT] -> [B, 1, EOUT]
// (softmax over a size-1 axis == 1.0, so the MLP branch is dead code)
//
// Two-kernel contiguous-stream version:
//   k1: 1024 blocks, each sums 64 full 4 KiB rows (wave reads 1 KiB contiguous),
//       nontemporal loads, partial per block -> d_ws (4 MiB)
//   k2: 8192 threads, each sums 32 partials for one output float4

constexpr int B_   = 32;
constexpr int S_   = 2048;
constexpr int EOUT = 1024;            // 2 * ENC_H
constexpr int RF4  = EOUT / 4;        // 256 float4 per row
constexpr int NS   = 32;              // s-split ways (blocks per batch)
constexpr int ROWS = S_ / NS;         // 64 rows per block

typedef float f4v __attribute__((ext_vector_type(4)));

__global__ __launch_bounds__(256) void partial_rowsum(const float* __restrict__ enc,
                                                      f4v* __restrict__ part) {
    const int blk = blockIdx.x;
    const int b   = blk >> 5;         // / NS
    const int sc  = blk & (NS - 1);
    const int tid = threadIdx.x;      // float4 column index 0..255

    const f4v* base = reinterpret_cast<const f4v*>(enc)
                    + (size_t)b * (S_ * RF4) + (size_t)sc * (ROWS * RF4) + tid;

    f4v a0 = {0.f, 0.f, 0.f, 0.f};
    f4v a1 = {0.f, 0.f, 0.f, 0.f};
    f4v a2 = {0.f, 0.f, 0.f, 0.f};
    f4v a3 = {0.f, 0.f, 0.f, 0.f};

    #pragma unroll
    for (int s = 0; s < ROWS; s += 4) {
        a0 += __builtin_nontemporal_load(base + (size_t)(s + 0) * RF4);
        a1 += __builtin_nontemporal_load(base + (size_t)(s + 1) * RF4);
        a2 += __builtin_nontemporal_load(base + (size_t)(s + 2) * RF4);
        a3 += __builtin_nontemporal_load(base + (size_t)(s + 3) * RF4);
    }
    part[(size_t)blk * RF4 + tid] = (a0 + a1) + (a2 + a3);
}

__global__ __launch_bounds__(256) void combine_partials(const f4v* __restrict__ part,
                                                        f4v* __restrict__ out) {
    const int gid = blockIdx.x * 256 + threadIdx.x;   // 0..8191
    const int b   = gid >> 8;                         // / RF4
    const int c   = gid & (RF4 - 1);

    const f4v* p = part + (size_t)b * (NS * RF4) + c;

    f4v a0 = {0.f,0.f,0.f,0.f}, a1 = {0.f,0.f,0.f,0.f};
    f4v a2 = {0.f,0.f,0.f,0.f}, a3 = {0.f,0.f,0.f,0.f};
    f4v a4 = {0.f,0.f,0.f,0.f}, a5 = {0.f,0.f,0.f,0.f};
    f4v a6 = {0.f,0.f,0.f,0.f}, a7 = {0.f,0.f,0.f,0.f};

    #pragma unroll
    for (int k = 0; k < NS; k += 8) {
        a0 += p[(size_t)(k + 0) * RF4];
        a1 += p[(size_t)(k + 1) * RF4];
        a2 += p[(size_t)(k + 2) * RF4];
        a3 += p[(size_t)(k + 3) * RF4];
        a4 += p[(size_t)(k + 4) * RF4];
        a5 += p[(size_t)(k + 5) * RF4];
        a6 += p[(size_t)(k + 6) * RF4];
        a7 += p[(size_t)(k + 7) * RF4];
    }
    out[gid] = ((a0 + a1) + (a2 + a3)) + ((a4 + a5) + (a6 + a7));
}

// ---------- fallback (round-1 single-kernel version) ----------
__device__ __forceinline__ void f4acc(float4& a, const float4 b) {
    a.x += b.x; a.y += b.y; a.z += b.z; a.w += b.w;
}

__global__ __launch_bounds__(256) void rowsum_kernel(const float* __restrict__ enc,
                                                     float* __restrict__ out) {
    const int bx  = blockIdx.x;
    const int b   = bx >> 5;
    const int ec  = bx & 31;
    const int tid = threadIdx.x;
    const int e4  = tid & 7;
    const int ss  = tid >> 3;

    const float4* base =
        reinterpret_cast<const float4*>(enc + (size_t)b * S_ * EOUT + ec * 32) + e4;
    constexpr int RS = EOUT / 4;

    float4 a0 = make_float4(0.f,0.f,0.f,0.f);
    float4 a1 = make_float4(0.f,0.f,0.f,0.f);
    float4 a2 = make_float4(0.f,0.f,0.f,0.f);
    float4 a3 = make_float4(0.f,0.f,0.f,0.f);

    #pragma unroll
    for (int s = 0; s < S_; s += 128) {
        f4acc(a0, base[(size_t)(s + ss) * RS]);
        f4acc(a1, base[(size_t)(s + ss + 32) * RS]);
        f4acc(a2, base[(size_t)(s + ss + 64) * RS]);
        f4acc(a3, base[(size_t)(s + ss + 96) * RS]);
    }
    f4acc(a0, a1); f4acc(a2, a3); f4acc(a0, a2);

    __shared__ float4 lds[256];
    lds[tid] = a0;
    __syncthreads();

    #pragma unroll
    for (int off = 128; off >= 8; off >>= 1) {
        if (tid < off) { float4 t = lds[tid + off]; f4acc(lds[tid], t); }
        __syncthreads();
    }
    if (tid < 8) {
        reinterpret_cast<float4*>(out + (size_t)b * EOUT + ec * 32)[tid] = lds[tid];
    }
}

extern "C" void kernel_launch(void* const* d_in, const int* in_sizes, int n_in,
                              void* d_out, int out_size, void* d_ws, size_t ws_size,
                              hipStream_t stream) {
    const float* enc = (const float*)d_in[0];
    float* out = (float*)d_out;

    const size_t ws_needed = (size_t)B_ * NS * EOUT * sizeof(float);  // 4 MiB
    if (ws_size >= ws_needed && d_ws != nullptr) {
        f4v* part = (f4v*)d_ws;
        partial_rowsum<<<dim3(B_ * NS), dim3(256), 0, stream>>>(enc, part);
        combine_partials<<<dim3((B_ * RF4) / 256), dim3(256), 0, stream>>>(part, (f4v*)out);
    } else {
        rowsum_kernel<<<dim3(B_ * NS), dim3(256), 0, stream>>>(enc, out);
    }
}